// Round 3
// baseline (12.264 us; speedup 1.0000x reference)
//
#include <hip/hip_runtime.h>

// Problem geometry (fixed by the reference's setup_inputs):
//   gt_boxes : (1,128,5) f32  [x1,y1,x2,y2,label]; num_boxes: scalar int.
//   feature H=W=256, im 1024 -> scale = 0.25 exactly.
// Output flat f32 (131074 elems):
//   [0..65535]       mask_pre (256x256)
//   [65536]          norms_pre
//   [65537..131072]  mask_cur (256x256)
//   [131073]         norms_cur
// Semantics: x_union[w] = OR over valid(label!=0) boxes of (w in [x1s,x2s)),
//            y_union likewise; mask = outer product; norms = 2*sum(mask)
//            (1.0 if sum==0 or n<=0).
//
// This round: single linear g-index mapping over the whole output so every
// store is an aligned float4 (the odd branch-1 base never matters); both
// branches' 256-bit x/y bitmasks built per block (lanes 0-127 = pre,
// 128-255 = cur) via LDS atomicOr; norms computed inline at g==65536/131073.

__device__ __forceinline__ void set_range(unsigned* bmw, int a, int b) {
    // set bits [a, b) in an 8-word (256-bit) bitmask
    if (b <= a) return;
    for (int w = (a >> 5); w <= ((b - 1) >> 5); ++w) {
        const int lo = max(a - w * 32, 0);
        const int hi = min(b - w * 32, 32);
        const unsigned hb = (hi == 32) ? 0xFFFFFFFFu : ((1u << hi) - 1u);
        const unsigned lb = (lo == 0) ? 0u : ((1u << lo) - 1u);
        atomicOr(&bmw[w], hb & ~lb);
    }
}

__device__ __forceinline__ float norms_of(const unsigned* bmw, int n) {
    int cx = 0, cy = 0;
    #pragma unroll
    for (int w = 0; w < 8; ++w) { cx += __popc(bmw[w]); cy += __popc(bmw[8 + w]); }
    const float s = 2.0f * (float)cx * (float)cy;
    return (n > 0 && s != 0.0f) ? s : 1.0f;
}

__global__ __launch_bounds__(256) void mask_gen_kernel(
    const float* __restrict__ boxes_pre, const int* __restrict__ n_pre,
    const float* __restrict__ boxes_cur, const int* __restrict__ n_cur,
    float* __restrict__ out, int nboxes, float scale)
{
    const int t = threadIdx.x;
    const int n0 = *n_pre;
    const int n1 = *n_cur;

    // bm[0..7]=x_pre, bm[8..15]=y_pre, bm[16..23]=x_cur, bm[24..31]=y_cur
    __shared__ unsigned bm[32];
    if (t < 32) bm[t] = 0u;
    __syncthreads();

    // lanes 0..127 (waves 0,1): pre boxes; lanes 128..255 (waves 2,3): cur.
    {
        const int branch = t >> 7;               // 0 or 1
        const int bi     = t & 127;              // box index
        const int n      = branch ? n1 : n0;
        if (n > 0 && bi < nboxes) {
            const float* __restrict__ b = (branch ? boxes_cur : boxes_pre) + bi * 5;
            if (b[4] != 0.0f) {
                int x1 = (int)truncf(b[0] * scale);
                int y1 = (int)truncf(b[1] * scale);
                int x2 = (int)truncf(b[2] * scale);
                int y2 = (int)truncf(b[3] * scale);
                x1 = min(max(x1, 0), 256); x2 = min(max(x2, 0), 256);
                y1 = min(max(y1, 0), 256); y2 = min(max(y2, 0), 256);
                unsigned* bmw = &bm[branch * 16];
                set_range(bmw,     x1, x2);
                set_range(bmw + 8, y1, y2);
            }
        }
    }
    __syncthreads();

    // Each thread writes 8 consecutive floats (two aligned float4s) of the
    // flat output. 64 blocks x 256 threads x 8 = 131072; block 0 thread 0
    // also writes the last two elements (g=131072, 131073).
    const int g0 = (blockIdx.x * 256 + t) * 8;

    float v[8];
    #pragma unroll
    for (int j = 0; j < 8; ++j) {
        const int g = g0 + j;
        const int branch = (g >= 65537) ? 1 : 0;
        const int local  = g - (branch ? 65537 : 0);
        const unsigned* bmw = &bm[branch * 16];
        if (local == 65536) {
            v[j] = norms_of(bmw, branch ? n1 : n0);
        } else {
            const int row = local >> 8;
            const int col = local & 255;
            const unsigned yb = (bmw[8 + (row >> 5)] >> (row & 31)) & 1u;
            const unsigned xb = (bmw[col >> 5] >> (col & 31)) & 1u;
            v[j] = (yb & xb) ? 1.0f : 0.0f;
        }
    }
    float4* o4 = (float4*)(out + g0);
    o4[0] = make_float4(v[0], v[1], v[2], v[3]);
    o4[1] = make_float4(v[4], v[5], v[6], v[7]);

    if (blockIdx.x == 0 && t == 0) {
        // g = 131072: branch 1, local 65535 -> row 255, col 255
        const unsigned* bmw = &bm[16];
        const unsigned yb = (bmw[8 + 7] >> 31) & 1u;
        const unsigned xb = (bmw[7] >> 31) & 1u;
        out[131072] = (yb & xb) ? 1.0f : 0.0f;
        out[131073] = norms_of(bmw, n1);
    }
}

extern "C" void kernel_launch(void* const* d_in, const int* in_sizes, int n_in,
                              void* d_out, int out_size, void* d_ws, size_t ws_size,
                              hipStream_t stream) {
    // Input order: im_data, feature, gt_boxes_pre, num_boxes_pre,
    //              gt_boxes_cur, num_boxes_cur.
    const float* boxes_pre = (const float*)d_in[2];
    const int*   n_pre     = (const int*)d_in[3];
    const float* boxes_cur = (const float*)d_in[4];
    const int*   n_cur     = (const int*)d_in[5];
    float* out = (float*)d_out;

    const int nboxes = in_sizes[2] / 5;   // 128
    const float scale = 0.25f;            // H/Himg = 256/1024

    mask_gen_kernel<<<64, 256, 0, stream>>>(
        boxes_pre, n_pre, boxes_cur, n_cur, out, nboxes, scale);
}

// Round 4
// 9.674 us; speedup vs baseline: 1.2677x; 1.2677x over previous
//
#include <hip/hip_runtime.h>

// Problem geometry (fixed by the reference's setup_inputs):
//   gt_boxes : (1,128,5) f32  [x1,y1,x2,y2,label]; num_boxes: scalar int.
//   feature H=W=256, im 1024 -> scale = 0.25 exactly.
// Output flat f32: mask_pre[65536], norms_pre[1], mask_cur[65536], norms_cur[1].
// Semantics: x_union[w] = OR over valid(label!=0) boxes of (w in [x1s,x2s)),
//            y_union likewise; mask = outer product; norms = 2*sum(mask),
//            (1.0 if sum==0 or n<=0).
//
// Round-2 structure (best measured: 9.56 us): box-parallel bit-range atomicOr
// into 256-bit x/y bitmasks (16 LDS words), scalar lane-coalesced mask stores.
// Round-3's float4 rewrite measured 12.26 us -> stores are not the bottleneck;
// we are at the launch-overhead floor. This round re-verifies round 2's number.

#define NSLICES 32   // blocks per branch; each block writes 8 mask rows

__global__ __launch_bounds__(256) void mask_gen_kernel(
    const float* __restrict__ boxes_pre, const int* __restrict__ n_pre,
    const float* __restrict__ boxes_cur, const int* __restrict__ n_cur,
    float* __restrict__ out, int nboxes, float scale)
{
    const int branch = blockIdx.x / NSLICES;   // 0 = pre, 1 = cur
    const int slice  = blockIdx.x % NSLICES;
    const float* __restrict__ boxes = branch ? boxes_cur : boxes_pre;
    const int n = branch ? *n_cur : *n_pre;
    float* __restrict__ mask_out = out + (size_t)branch * 65537;

    const int t = threadIdx.x;

    // bm[0..7] = x_union bits (256), bm[8..15] = y_union bits (256).
    __shared__ unsigned int bm[16];
    if (t < 16) bm[t] = 0u;
    __syncthreads();

    if (n > 0 && t < nboxes) {
        const float* __restrict__ b = boxes + t * 5;
        const float lab = b[4];
        if (lab != 0.0f) {
            int x1 = (int)truncf(b[0] * scale);
            int y1 = (int)truncf(b[1] * scale);
            int x2 = (int)truncf(b[2] * scale);
            int y2 = (int)truncf(b[3] * scale);
            x1 = min(max(x1, 0), 256); x2 = min(max(x2, 0), 256);
            y1 = min(max(y1, 0), 256); y2 = min(max(y2, 0), 256);
            if (x2 > x1) {
                for (int w = (x1 >> 5); w <= ((x2 - 1) >> 5); ++w) {
                    const int lo = max(x1 - w * 32, 0);
                    const int hi = min(x2 - w * 32, 32);
                    const unsigned hb = (hi == 32) ? 0xFFFFFFFFu : ((1u << hi) - 1u);
                    const unsigned lb = (lo == 0) ? 0u : ((1u << lo) - 1u);
                    atomicOr(&bm[w], hb & ~lb);
                }
            }
            if (y2 > y1) {
                for (int w = (y1 >> 5); w <= ((y2 - 1) >> 5); ++w) {
                    const int lo = max(y1 - w * 32, 0);
                    const int hi = min(y2 - w * 32, 32);
                    const unsigned hb = (hi == 32) ? 0xFFFFFFFFu : ((1u << hi) - 1u);
                    const unsigned lb = (lo == 0) ? 0u : ((1u << lo) - 1u);
                    atomicOr(&bm[8 + w], hb & ~lb);
                }
            }
        }
    }
    __syncthreads();

    if (slice == 0 && t == 0) {
        int cx = 0, cy = 0;
        #pragma unroll
        for (int w = 0; w < 8; ++w) { cx += __popc(bm[w]); cy += __popc(bm[8 + w]); }
        const float s = 2.0f * (float)cx * (float)cy;
        mask_out[65536] = (n > 0 && s != 0.0f) ? s : 1.0f;
    }

    // Write 8 rows of the 256x256 mask. Branch-1 base offset is odd (65537
    // floats) so stores stay scalar (4B) but lane-coalesced.
    const int row  = slice * 8 + (t >> 5);   // 0..255
    const int lane = t & 31;
    const unsigned yb = (bm[8 + (row >> 5)] >> (row & 31)) & 1u;
    float* __restrict__ rowp = mask_out + (size_t)row * 256;
    #pragma unroll
    for (int j = 0; j < 8; ++j) {
        const unsigned xb = (bm[j] >> lane) & 1u;   // col = lane + 32j -> word j
        rowp[lane + j * 32] = (yb & xb) ? 1.0f : 0.0f;
    }
}

extern "C" void kernel_launch(void* const* d_in, const int* in_sizes, int n_in,
                              void* d_out, int out_size, void* d_ws, size_t ws_size,
                              hipStream_t stream) {
    // Input order: im_data, feature, gt_boxes_pre, num_boxes_pre,
    //              gt_boxes_cur, num_boxes_cur.
    const float* boxes_pre = (const float*)d_in[2];
    const int*   n_pre     = (const int*)d_in[3];
    const float* boxes_cur = (const float*)d_in[4];
    const int*   n_cur     = (const int*)d_in[5];
    float* out = (float*)d_out;

    const int nboxes = in_sizes[2] / 5;   // 128
    const float scale = 0.25f;            // H/Himg = 256/1024

    mask_gen_kernel<<<2 * NSLICES, 256, 0, stream>>>(
        boxes_pre, n_pre, boxes_cur, n_cur, out, nboxes, scale);
}